// Round 4
// baseline (7034.893 us; speedup 1.0000x reference)
//
#include <hip/hip_runtime.h>
#include <hip/hip_bf16.h>
#include <math.h>

// Problem constants: B=64, L=256, E=1024, H=1024
#define Mx      16384
#define TWOH    2048
#define FIVEH   5120
#define NSTEPS  255
#define NBLK    64      // persistent chain grid size (<= 256 CUs -> co-resident)

typedef __attribute__((ext_vector_type(8))) short short8;
typedef __attribute__((ext_vector_type(8))) unsigned short ushort8;
typedef __attribute__((ext_vector_type(4))) float f32x4;

__device__ __forceinline__ float bf2f(unsigned short u) {
    union { unsigned int i; float f; } v; v.i = ((unsigned int)u) << 16; return v.f;
}
__device__ __forceinline__ unsigned short f2bf(float f) {
    union { float f; unsigned int u; } v; v.f = f;
    return (unsigned short)((v.u + 0x7FFFu + ((v.u >> 16) & 1u)) >> 16);
}
__device__ __forceinline__ short8 cvt8(float4 u0, float4 u1) {
    short8 s;
    s[0] = (short)f2bf(u0.x); s[1] = (short)f2bf(u0.y);
    s[2] = (short)f2bf(u0.z); s[3] = (short)f2bf(u0.w);
    s[4] = (short)f2bf(u1.x); s[5] = (short)f2bf(u1.y);
    s[6] = (short)f2bf(u1.z); s[7] = (short)f2bf(u1.w);
    return s;
}
__device__ __forceinline__ float sigf(float x) { return 1.0f / (1.0f + expf(-x)); }

__global__ void zero_stats(float* __restrict__ p) {
    p[blockIdx.x * 256 + threadIdx.x] = 0.0f;   // grid 20: sumb+sqb+barrier page
}

// Pack W[K,N] fp32 -> MFMA-B-fragment layout: out[kq][n][j] = bf16(W[kq*8+j][n])
__global__ void pack_w(const float* __restrict__ W, unsigned short* __restrict__ out, int N)
{
    const int kq = blockIdx.x;
    for (int n = threadIdx.x; n < N; n += 256) {
        ushort8 o;
#pragma unroll
        for (int j = 0; j < 8; j++)
            o[j] = f2bf(W[(size_t)(kq * 8 + j) * N + n]);
        *(ushort8*)&out[((size_t)kq * N + n) * 8] = o;
    }
}

// ---------------------------------------------------------------------------
// P = sentence @ W_word (b_word cancels through BN). Stores P bf16 into
// h_sent/c_sent; accumulates per-column sum/sumsq. 128x128 tile, 4 waves,
// MFMA 16x16x32 bf16, A cvt in regs, B from packed layout.
// ---------------------------------------------------------------------------
__global__ __launch_bounds__(256) void gemm_bn_mfma(
    const float* __restrict__ A, const unsigned short* __restrict__ Bpk,
    unsigned short* __restrict__ h_out, unsigned short* __restrict__ c_out,
    float* __restrict__ sumb, float* __restrict__ sqb)
{
    const int tid = threadIdx.x;
    const int wave = tid >> 6, lane = tid & 63;
    const int q = lane >> 4, r = lane & 15;
    const int m0 = blockIdx.y * 128 + (wave >> 1) * 64;
    const int n0 = blockIdx.x * 128 + (wave & 1) * 64;

    f32x4 acc[4][4];
#pragma unroll
    for (int i = 0; i < 4; i++)
#pragma unroll
        for (int j = 0; j < 4; j++) acc[i][j] = (f32x4)0.0f;

    for (int k0 = 0; k0 < 1024; k0 += 32) {
        const int kl = k0 + q * 8;
        short8 a[4], b[4];
#pragma unroll
        for (int mi = 0; mi < 4; mi++) {
            const float* ap = A + (size_t)(m0 + mi * 16 + r) * 1024 + kl;
            a[mi] = cvt8(*(const float4*)ap, *(const float4*)(ap + 4));
        }
#pragma unroll
        for (int ni = 0; ni < 4; ni++)
            b[ni] = *(const short8*)&Bpk[((size_t)(kl >> 3) * TWOH + n0 + ni * 16 + r) * 8];
#pragma unroll
        for (int mi = 0; mi < 4; mi++)
#pragma unroll
            for (int ni = 0; ni < 4; ni++)
                acc[mi][ni] = __builtin_amdgcn_mfma_f32_16x16x32_bf16(a[mi], b[ni], acc[mi][ni], 0, 0, 0);
    }

#pragma unroll
    for (int ni = 0; ni < 4; ni++) {
        float s = 0.0f, qq = 0.0f;
#pragma unroll
        for (int mi = 0; mi < 4; mi++)
#pragma unroll
            for (int rg = 0; rg < 4; rg++) {
                const float v = acc[mi][ni][rg];
                s += v; qq += v * v;
            }
        s += __shfl_xor(s, 16); s += __shfl_xor(s, 32);
        qq += __shfl_xor(qq, 16); qq += __shfl_xor(qq, 32);
        if (lane < 16) {
            atomicAdd(&sumb[n0 + ni * 16 + r], s);
            atomicAdd(&sqb[n0 + ni * 16 + r], qq);
        }
    }

    const bool is_h = (n0 < 1024);
    unsigned short* dst = is_h ? h_out : c_out;
    const int cb = is_h ? n0 : n0 - 1024;
#pragma unroll
    for (int mi = 0; mi < 4; mi++)
#pragma unroll
        for (int rg = 0; rg < 4; rg++) {
            const size_t row = (size_t)(m0 + mi * 16 + q * 4 + rg);
#pragma unroll
            for (int ni = 0; ni < 4; ni++)
                dst[row * 1024 + cb + ni * 16 + r] = f2bf(acc[mi][ni][rg]);
        }
}

__global__ void bn_finalize(const float* __restrict__ sumb, const float* __restrict__ sqb,
                            const float* __restrict__ gamma, const float* __restrict__ beta,
                            float* __restrict__ scale, float* __restrict__ shift)
{
    const int c = blockIdx.x * 256 + threadIdx.x;  // grid 8
    const float inv_n = 1.0f / 16384.0f;
    const float mean = sumb[c] * inv_n;
    const float var = sqb[c] * inv_n - mean * mean;
    const float sc = gamma[c] * rsqrtf(var + 1e-5f);
    scale[c] = sc;
    shift[c] = beta[c] - mean * sc;
}

// In-place BN affine on bf16 h_sent / c_sent.
__global__ void bn_apply(unsigned short* __restrict__ hs, unsigned short* __restrict__ cs,
                         const float* __restrict__ scale, const float* __restrict__ shift)
{
    const bool ish = blockIdx.x < 8192;
    unsigned short* p = ish ? hs : cs;
    const size_t base = ((size_t)(blockIdx.x & 8191) * 256 + threadIdx.x) * 8;
    const int col = (int)(base & 1023);
    const int cb = ish ? col : col + 1024;
    ushort8 v = *(ushort8*)&p[base];
#pragma unroll
    for (int e = 0; e < 8; e++)
        v[e] = f2bf(bf2f(v[e]) * scale[cb + e] + shift[cb + e]);
    *(ushort8*)&p[base] = v;
}

// ---------------------------------------------------------------------------
// Persistent chain kernel: all 255 reduce steps in one launch.
// 64 blocks x 256 threads, block owns 16 cell-cols (all 5 gates). Device-scope
// atomic barrier between steps (G16: device-scope atomics/fences for cross-XCD).
// ---------------------------------------------------------------------------
__device__ __forceinline__ void grid_barrier(unsigned* ctr, unsigned target) {
    __syncthreads();
    if (threadIdx.x == 0) {
        __threadfence();  // release our global writes
        __hip_atomic_fetch_add(ctr, 1u, __ATOMIC_ACQ_REL, __HIP_MEMORY_SCOPE_AGENT);
        while (__hip_atomic_load(ctr, __ATOMIC_ACQUIRE, __HIP_MEMORY_SCOPE_AGENT) < target)
            __builtin_amdgcn_s_sleep(2);
    }
    __syncthreads();
    __threadfence();  // acquire: invalidate stale cached lines before reads
}

__global__ __launch_bounds__(256) void chain_persistent(
    const unsigned short* __restrict__ h_sent, const unsigned short* __restrict__ c_sent,
    const unsigned short* __restrict__ Wpk, const float* __restrict__ b_red,
    unsigned short* __restrict__ hA, float* __restrict__ cA,   // dbuf [2][64*1024]
    float* __restrict__ out, unsigned* __restrict__ ctr)
{
    __shared__ float Gs[2][64][16][5];   // 40 KB
    const int tid = threadIdx.x, w = tid >> 6, lane = tid & 63;
    const int q = lane >> 4, r = lane & 15;
    const int c0 = blockIdx.x * 16;
    const int kw = w * 512;

    for (int j = 1; j <= NSTEPS; j++) {
        // A source for k<1024 (left child h): step 1 = word 0 of h_sent
        const unsigned short* aP;
        size_t astr;
        if (j == 1) { aP = h_sent; astr = 262144; }
        else        { aP = hA + ((size_t)((j - 1) & 1) << 16); astr = 1024; }

        f32x4 acc[4][5];
#pragma unroll
        for (int i = 0; i < 4; i++)
#pragma unroll
            for (int g = 0; g < 5; g++) acc[i][g] = (f32x4)0.0f;

        for (int ks = 0; ks < 512; ks += 32) {
            const int kl = kw + ks + q * 8;
            short8 a[4], b[5];
            if (kw < 1024) {
#pragma unroll
                for (int mi = 0; mi < 4; mi++)
                    a[mi] = *(const short8*)&aP[(size_t)(mi * 16 + r) * astr + kl];
            } else {
#pragma unroll
                for (int mi = 0; mi < 4; mi++)
                    a[mi] = *(const short8*)&h_sent[((size_t)(mi * 16 + r) * 256 + j) * 1024 + (kl - 1024)];
            }
#pragma unroll
            for (int g = 0; g < 5; g++)
                b[g] = *(const short8*)&Wpk[((size_t)(kl >> 3) * FIVEH + g * 1024 + c0 + r) * 8];
#pragma unroll
            for (int mi = 0; mi < 4; mi++)
#pragma unroll
                for (int g = 0; g < 5; g++)
                    acc[mi][g] = __builtin_amdgcn_mfma_f32_16x16x32_bf16(a[mi], b[g], acc[mi][g], 0, 0, 0);
        }

        // cross-wave K reduction through LDS
        if (w >= 2) {
#pragma unroll
            for (int mi = 0; mi < 4; mi++)
#pragma unroll
                for (int g = 0; g < 5; g++)
#pragma unroll
                    for (int rg = 0; rg < 4; rg++)
                        Gs[w - 2][mi * 16 + q * 4 + rg][r][g] = acc[mi][g][rg];
        }
        __syncthreads();
        if (w < 2) {
#pragma unroll
            for (int mi = 0; mi < 4; mi++)
#pragma unroll
                for (int g = 0; g < 5; g++)
#pragma unroll
                    for (int rg = 0; rg < 4; rg++)
                        Gs[w][mi * 16 + q * 4 + rg][r][g] += acc[mi][g][rg];
        }
        __syncthreads();

        // LSTM elementwise: block's 1024 cells (64 rows x 16 cols), 4/thread
        const size_t wr = (size_t)(j & 1) << 16;
#pragma unroll
        for (int u = 0; u < 4; u++) {
            const int cc = tid * 4 + u;
            const int m = cc >> 4, cl = cc & 15;
            const int col = c0 + cl;
            float g[5];
#pragma unroll
            for (int gg = 0; gg < 5; gg++)
                g[gg] = Gs[0][m][cl][gg] + Gs[1][m][cl][gg] + b_red[gg * 1024 + col];
            const float clv = (j == 1)
                ? bf2f(c_sent[(size_t)m * 262144 + col])
                : cA[((size_t)((j - 1) & 1) << 16) + (size_t)m * 1024 + col];
            const float crv = bf2f(c_sent[((size_t)m * 256 + j) * 1024 + col]);
            const float cn = sigf(g[1]) * clv + sigf(g[2]) * crv + sigf(g[0]) * tanhf(g[4]);
            const float hn = sigf(g[3]) * tanhf(cn);
            cA[wr + (size_t)m * 1024 + col] = cn;
            hA[wr + (size_t)m * 1024 + col] = f2bf(hn);
            if (j == NSTEPS) out[(size_t)m * 1024 + col] = hn;
        }

        grid_barrier(ctr, (unsigned)(NBLK * j));
    }
}

// ---------------------------------------------------------------------------
extern "C" void kernel_launch(void* const* d_in, const int* in_sizes, int n_in,
                              void* d_out, int out_size, void* d_ws, size_t ws_size,
                              hipStream_t stream)
{
    (void)in_sizes; (void)n_in; (void)out_size; (void)ws_size;
    const float* sentence = (const float*)d_in[0];
    const float* W_word   = (const float*)d_in[3];
    // d_in[4] b_word cancels through BatchNorm -> unused
    const float* gamma    = (const float*)d_in[5];
    const float* beta     = (const float*)d_in[6];
    const float* W_reduce = (const float*)d_in[7];
    const float* b_reduce = (const float*)d_in[8];

    // workspace layout (~108.8 MB)
    char* ws = (char*)d_ws;
    size_t off = 0;
    float* sumb   = (float*)(ws + off); off += 8192;
    float* sqb    = (float*)(ws + off); off += 8192;
    unsigned* ctr = (unsigned*)(ws + off); off += 4096;     // barrier counter (zeroed)
    float* scale  = (float*)(ws + off); off += 8192;
    float* shift  = (float*)(ws + off); off += 8192;
    unsigned short* hA = (unsigned short*)(ws + off); off += 262144;   // [2][64][1024] bf16
    float* cA          = (float*)(ws + off); off += 524288;            // [2][64][1024] f32
    unsigned short* Wwpk = (unsigned short*)(ws + off); off += 4194304;
    unsigned short* Wpk  = (unsigned short*)(ws + off); off += 41943040;
    unsigned short* h_sent = (unsigned short*)(ws + off); off += 33554432;
    unsigned short* c_sent = (unsigned short*)(ws + off); off += 33554432;

    pack_w<<<128, 256, 0, stream>>>(W_word, Wwpk, TWOH);
    pack_w<<<256, 256, 0, stream>>>(W_reduce, Wpk, FIVEH);
    zero_stats<<<20, 256, 0, stream>>>(sumb);   // zeroes sumb+sqb+ctr page

    gemm_bn_mfma<<<dim3(16, 128), 256, 0, stream>>>(
        sentence, Wwpk, h_sent, c_sent, sumb, sqb);
    bn_finalize<<<8, 256, 0, stream>>>(sumb, sqb, gamma, beta, scale, shift);
    bn_apply<<<16384, 256, 0, stream>>>(h_sent, c_sent, scale, shift);

    chain_persistent<<<NBLK, 256, 0, stream>>>(
        h_sent, c_sent, Wpk, b_reduce, hA, cA, (float*)d_out, ctr);
}